// Round 4
// baseline (5035.891 us; speedup 1.0000x reference)
//
#include <hip/hip_runtime.h>
#include <math.h>

// Problem constants
#define B_    8192
#define DIN_  1024
#define HID_  2048
#define LAT_  256
#define KC_   4096   // codebook size

// ---------------------------------------------------------------------------
// fp32 GEMM (decoder): C[M,N] = act(A[M,K] @ W[K,N] + bias[N])
// ---------------------------------------------------------------------------
__device__ __forceinline__ float gelu_exact_f32(float v) {
    return 0.5f * v * (1.0f + erff(v * 0.70710678118654752440f));
}

template <bool GELU>
__global__ __launch_bounds__(256) void gemm_bias_act_f32(
    const float* __restrict__ A, const float* __restrict__ W,
    const float* __restrict__ bias, float* __restrict__ C,
    int M, int N, int K)
{
    __shared__ float As[16][68];
    __shared__ float Ws[16][64];

    const int tid = threadIdx.x;
    const int tx = tid & 15;
    const int ty = tid >> 4;
    const int m0 = blockIdx.x * 64;
    const int n0 = blockIdx.y * 64;

    float acc[4][4] = {};

    for (int k0 = 0; k0 < K; k0 += 16) {
#pragma unroll
        for (int i = 0; i < 4; ++i) {
            int m = (tid >> 4) + i * 16;
            As[tid & 15][m] = A[(size_t)(m0 + m) * K + k0 + (tid & 15)];
        }
#pragma unroll
        for (int i = 0; i < 4; ++i) {
            int k = (tid >> 6) + i * 4;
            Ws[k][tid & 63] = W[(size_t)(k0 + k) * N + n0 + (tid & 63)];
        }
        __syncthreads();
#pragma unroll
        for (int kk = 0; kk < 16; ++kk) {
            const float4 a = *reinterpret_cast<const float4*>(&As[kk][ty * 4]);
            const float4 b = *reinterpret_cast<const float4*>(&Ws[kk][tx * 4]);
            const float av[4] = {a.x, a.y, a.z, a.w};
            const float bv[4] = {b.x, b.y, b.z, b.w};
#pragma unroll
            for (int i = 0; i < 4; ++i)
#pragma unroll
                for (int j = 0; j < 4; ++j)
                    acc[i][j] = fmaf(av[i], bv[j], acc[i][j]);
        }
        __syncthreads();
    }

    const int nb = n0 + tx * 4;
    const float4 bvec = *reinterpret_cast<const float4*>(&bias[nb]);
    const float bb[4] = {bvec.x, bvec.y, bvec.z, bvec.w};
#pragma unroll
    for (int i = 0; i < 4; ++i) {
        int m = m0 + ty * 4 + i;
        float4 r;
        float rr[4];
#pragma unroll
        for (int j = 0; j < 4; ++j) {
            float v = acc[i][j] + bb[j];
            rr[j] = GELU ? gelu_exact_f32(v) : v;
        }
        r.x = rr[0]; r.y = rr[1]; r.z = rr[2]; r.w = rr[3];
        *reinterpret_cast<float4*>(&C[(size_t)m * N + nb]) = r;
    }
}

// ---------------------------------------------------------------------------
// fp64-accumulate GEMM (encoder): fp32 in/out, exact products in fp64.
// ---------------------------------------------------------------------------
template <bool GELU>
__global__ __launch_bounds__(256) void gemm_bias_act_f64acc(
    const float* __restrict__ A, const float* __restrict__ W,
    const float* __restrict__ bias, float* __restrict__ C,
    int M, int N, int K)
{
    __shared__ float As[16][68];
    __shared__ float Ws[16][64];

    const int tid = threadIdx.x;
    const int tx = tid & 15;
    const int ty = tid >> 4;
    const int m0 = blockIdx.x * 64;
    const int n0 = blockIdx.y * 64;

    double acc[4][4] = {};

    for (int k0 = 0; k0 < K; k0 += 16) {
#pragma unroll
        for (int i = 0; i < 4; ++i) {
            int m = (tid >> 4) + i * 16;
            As[tid & 15][m] = A[(size_t)(m0 + m) * K + k0 + (tid & 15)];
        }
#pragma unroll
        for (int i = 0; i < 4; ++i) {
            int k = (tid >> 6) + i * 4;
            Ws[k][tid & 63] = W[(size_t)(k0 + k) * N + n0 + (tid & 63)];
        }
        __syncthreads();
#pragma unroll
        for (int kk = 0; kk < 16; ++kk) {
            const float4 a = *reinterpret_cast<const float4*>(&As[kk][ty * 4]);
            const float4 b = *reinterpret_cast<const float4*>(&Ws[kk][tx * 4]);
            const double av[4] = {(double)a.x, (double)a.y, (double)a.z, (double)a.w};
            const double bv[4] = {(double)b.x, (double)b.y, (double)b.z, (double)b.w};
#pragma unroll
            for (int i = 0; i < 4; ++i)
#pragma unroll
                for (int j = 0; j < 4; ++j)
                    acc[i][j] = fma(av[i], bv[j], acc[i][j]);
        }
        __syncthreads();
    }

    const int nb = n0 + tx * 4;
    const float4 bvec = *reinterpret_cast<const float4*>(&bias[nb]);
    const double bb[4] = {(double)bvec.x, (double)bvec.y, (double)bvec.z, (double)bvec.w};
#pragma unroll
    for (int i = 0; i < 4; ++i) {
        int m = m0 + ty * 4 + i;
        float rr[4];
#pragma unroll
        for (int j = 0; j < 4; ++j) {
            double v = acc[i][j] + bb[j];
            if (GELU) v = 0.5 * v * (1.0 + erf(v * 0.70710678118654752440));
            rr[j] = (float)v;
        }
        float4 r; r.x = rr[0]; r.y = rr[1]; r.z = rr[2]; r.w = rr[3];
        *reinterpret_cast<float4*>(&C[(size_t)m * N + nb]) = r;
    }
}

// ---------------------------------------------------------------------------
// Transpose embed [4096,256] -> embedT [256,4096]
// ---------------------------------------------------------------------------
__global__ __launch_bounds__(256) void transpose_embed(
    const float* __restrict__ E, float* __restrict__ ET)
{
    __shared__ float t[32][33];
    const int c0 = blockIdx.x * 32;
    const int l0 = blockIdx.y * 32;
    const int x = threadIdx.x;
    const int y = threadIdx.y;
#pragma unroll
    for (int i = 0; i < 4; ++i)
        t[y + i * 8][x] = E[(size_t)(c0 + y + i * 8) * LAT_ + l0 + x];
    __syncthreads();
#pragma unroll
    for (int i = 0; i < 4; ++i)
        ET[(size_t)(l0 + y + i * 8) * KC_ + c0 + x] = t[x][y + i * 8];
}

// ---------------------------------------------------------------------------
// rowsq[r] = fp32( fp64 sum of X[r,:].^2 ), rows of width LAT_=256.
// Optionally zeroes the loss slot (block 0).
// ---------------------------------------------------------------------------
__global__ __launch_bounds__(64) void rowsq_kernel(
    const float* __restrict__ X, float* __restrict__ out,
    float* __restrict__ loss_slot)
{
    const int r = blockIdx.x;
    const float4 v = reinterpret_cast<const float4*>(X + (size_t)r * LAT_)[threadIdx.x];
    double s = (double)v.x * v.x + (double)v.y * v.y + (double)v.z * v.z + (double)v.w * v.w;
#pragma unroll
    for (int off = 32; off; off >>= 1) s += __shfl_down(s, off, 64);
    if (threadIdx.x == 0) {
        out[r] = (float)s;
        if (loss_slot != nullptr && r == 0) *loss_slot = 0.0f;
    }
}

// ---------------------------------------------------------------------------
// Fused distance + argmin, mimicking numpy's fp32 dist rounding:
//   dist32 = fp32( fp32(zsq + esq) - fp32(2 * dot_f64) ), argmin first-index.
// The ulp(~77) quantization of dist32 is what generates the reference's ties;
// first-index tie-break then matches np.argmin.
// ---------------------------------------------------------------------------
__global__ __launch_bounds__(256) void vq_argmin(
    const float* __restrict__ Z,     // [B,256]
    const float* __restrict__ ET,    // [256,4096]
    const float* __restrict__ esq,   // [4096] fp32
    const float* __restrict__ zsq,   // [B]    fp32
    float* __restrict__ pval, int* __restrict__ pidx)  // [B,8]
{
    __shared__ float Zs[16][68];
    __shared__ float Es[16][64];
    __shared__ float rv[64][16];
    __shared__ int   ri[64][16];

    const int tid = threadIdx.x;
    const int tx = tid & 15;
    const int ty = tid >> 4;
    const int m0 = blockIdx.x * 64;
    const int split = blockIdx.y;
    const int nbeg = split * (KC_ / 8);

    float zsqv[4];
#pragma unroll
    for (int i = 0; i < 4; ++i) zsqv[i] = zsq[m0 + ty * 4 + i];

    float bestv[4];
    int   besti[4];
#pragma unroll
    for (int i = 0; i < 4; ++i) { bestv[i] = 3.4e38f; besti[i] = 0; }

    for (int n0 = nbeg; n0 < nbeg + (KC_ / 8); n0 += 64) {
        double acc[4][4] = {};
        for (int k0 = 0; k0 < LAT_; k0 += 16) {
#pragma unroll
            for (int i = 0; i < 4; ++i) {
                int m = (tid >> 4) + i * 16;
                Zs[tid & 15][m] = Z[(size_t)(m0 + m) * LAT_ + k0 + (tid & 15)];
            }
#pragma unroll
            for (int i = 0; i < 4; ++i) {
                int k = (tid >> 6) + i * 4;
                Es[k][tid & 63] = ET[(size_t)(k0 + k) * KC_ + n0 + (tid & 63)];
            }
            __syncthreads();
#pragma unroll
            for (int kk = 0; kk < 16; ++kk) {
                const float4 a = *reinterpret_cast<const float4*>(&Zs[kk][ty * 4]);
                const float4 b = *reinterpret_cast<const float4*>(&Es[kk][tx * 4]);
                const double av[4] = {(double)a.x, (double)a.y, (double)a.z, (double)a.w};
                const double bv[4] = {(double)b.x, (double)b.y, (double)b.z, (double)b.w};
#pragma unroll
                for (int i = 0; i < 4; ++i)
#pragma unroll
                    for (int j = 0; j < 4; ++j)
                        acc[i][j] = fma(av[i], bv[j], acc[i][j]);
            }
            __syncthreads();
        }
        // numpy-mimicking fp32 scoring
#pragma unroll
        for (int j = 0; j < 4; ++j) {
            const int n = n0 + tx * 4 + j;
            const float es = esq[n];
#pragma unroll
            for (int i = 0; i < 4; ++i) {
                const float S   = zsqv[i] + es;              // fp32 add
                const float t2m = (float)(2.0 * acc[i][j]);  // exact*2, one round
                const float sc  = S - t2m;                   // fp32 sub
                if (sc < bestv[i] || (sc == bestv[i] && n < besti[i])) {
                    bestv[i] = sc; besti[i] = n;
                }
            }
        }
    }
#pragma unroll
    for (int i = 0; i < 4; ++i) { rv[ty * 4 + i][tx] = bestv[i]; ri[ty * 4 + i][tx] = besti[i]; }
    __syncthreads();
    if (tid < 64) {
        float bv = rv[tid][0]; int bi = ri[tid][0];
#pragma unroll
        for (int t = 1; t < 16; ++t) {
            const float v = rv[tid][t]; const int ix = ri[tid][t];
            if (v < bv || (v == bv && ix < bi)) { bv = v; bi = ix; }
        }
        pval[(m0 + tid) * 8 + split] = bv;
        pidx[(m0 + tid) * 8 + split] = bi;
    }
}

// ---------------------------------------------------------------------------
// Finalize: reduce 8 partials -> index (as float), gather z_q, loss atomics
// ---------------------------------------------------------------------------
__global__ __launch_bounds__(64) void vq_finalize(
    const float* __restrict__ pval, const int* __restrict__ pidx,
    const float* __restrict__ Z, const float* __restrict__ E,
    float* __restrict__ zq, float* __restrict__ out_idx,
    float* __restrict__ loss_slot)
{
    const int row = blockIdx.x;
    __shared__ int sidx;
    if (threadIdx.x == 0) {
        float bv = pval[row * 8]; int bi = pidx[row * 8];
#pragma unroll
        for (int s = 1; s < 8; ++s) {
            const float v = pval[row * 8 + s]; const int ix = pidx[row * 8 + s];
            if (v < bv || (v == bv && ix < bi)) { bv = v; bi = ix; }
        }
        sidx = bi;
        out_idx[row] = (float)bi;
    }
    __syncthreads();
    const int idx = sidx;
    const float4 e = reinterpret_cast<const float4*>(E + (size_t)idx * LAT_)[threadIdx.x];
    const float4 z = reinterpret_cast<const float4*>(Z + (size_t)row * LAT_)[threadIdx.x];
    reinterpret_cast<float4*>(zq + (size_t)row * LAT_)[threadIdx.x] = e;
    const float dx = z.x - e.x, dy = z.y - e.y, dz = z.z - e.z, dw = z.w - e.w;
    float s = dx * dx + dy * dy + dz * dz + dw * dw;
#pragma unroll
    for (int off = 32; off; off >>= 1) s += __shfl_down(s, off, 64);
    if (threadIdx.x == 0)
        atomicAdd(loss_slot, s * (1.25f / ((float)B_ * (float)LAT_)));
}

// ---------------------------------------------------------------------------
extern "C" void kernel_launch(void* const* d_in, const int* in_sizes, int n_in,
                              void* d_out, int out_size, void* d_ws, size_t ws_size,
                              hipStream_t stream)
{
    const float* x   = (const float*)d_in[0];
    const float* W1  = (const float*)d_in[1];
    const float* b1  = (const float*)d_in[2];
    const float* W2  = (const float*)d_in[3];
    const float* b2  = (const float*)d_in[4];
    const float* W3  = (const float*)d_in[5];
    const float* b3  = (const float*)d_in[6];
    const float* emb = (const float*)d_in[7];
    const float* D1  = (const float*)d_in[8];
    const float* d1  = (const float*)d_in[9];
    const float* D2  = (const float*)d_in[10];
    const float* d2  = (const float*)d_in[11];
    const float* D3  = (const float*)d_in[12];
    const float* d3  = (const float*)d_in[13];
    float* out = (float*)d_out;

    // Workspace layout — strictly disjoint regions (≈149 MB; round 1 proved
    // ws_size ≥ 156 MB works):
    //   [  0, 64M)  h1 / g1
    //   [ 64,128M)  h2 / g2
    //   [128,136M)  ze
    //   [136,144M)  zq
    //   [144,148M)  embT
    //   [148M, +16K)       esq  (fp32)
    //   [148M+16K, +32K)   zsq  (fp32)
    //   [148M+48K, +256K)  pval (fp32)
    //   [148M+304K,+256K)  pidx (int)
    char* ws = (char*)d_ws;
    float* bufA = (float*)(ws);
    float* bufB = (float*)(ws + 67108864);
    float* ze   = (float*)(ws + 134217728);
    float* zq   = (float*)(ws + 142606336);
    float* embT = (float*)(ws + 150994944);
    float* esq  = (float*)(ws + 155189248);
    float* zsq  = (float*)(ws + 155205632);
    float* pval = (float*)(ws + 155238400);
    int*   pidx = (int*)  (ws + 155500544);

    float* loss_slot = out + (size_t)B_ * DIN_;     // d_out[8388608]
    float* out_idx   = loss_slot + 1;               // d_out[8388609..]

    // codebook prep (esq also zeroes loss slot)
    rowsq_kernel<<<KC_, 64, 0, stream>>>(emb, esq, loss_slot);
    transpose_embed<<<dim3(KC_ / 32, LAT_ / 32), dim3(32, 8), 0, stream>>>(emb, embT);

    // encoder — fp64 accumulation
    gemm_bias_act_f64acc<true ><<<dim3(B_ / 64, HID_ / 64), 256, 0, stream>>>(x,    W1, b1, bufA, B_, HID_, DIN_);
    gemm_bias_act_f64acc<true ><<<dim3(B_ / 64, HID_ / 64), 256, 0, stream>>>(bufA, W2, b2, bufB, B_, HID_, HID_);
    gemm_bias_act_f64acc<false><<<dim3(B_ / 64, LAT_ / 64), 256, 0, stream>>>(bufB, W3, b3, ze,   B_, LAT_, HID_);

    // z row norms (fp32-rounded)
    rowsq_kernel<<<B_, 64, 0, stream>>>(ze, zsq, nullptr);

    // VQ — numpy-fp32-mimicking scores, first-index tie-break
    vq_argmin<<<dim3(B_ / 64, 8), 256, 0, stream>>>(ze, embT, esq, zsq, pval, pidx);
    vq_finalize<<<B_, 64, 0, stream>>>(pval, pidx, ze, emb, zq, out_idx, loss_slot);

    // decoder — fp32
    gemm_bias_act_f32<true ><<<dim3(B_ / 64, HID_ / 64), 256, 0, stream>>>(zq,   D1, d1, bufA, B_, HID_, LAT_);
    gemm_bias_act_f32<true ><<<dim3(B_ / 64, HID_ / 64), 256, 0, stream>>>(bufA, D2, d2, bufB, B_, HID_, HID_);
    gemm_bias_act_f32<false><<<dim3(B_ / 64, DIN_ / 64), 256, 0, stream>>>(bufB, D3, d3, out,  B_, DIN_, HID_);
}

// Round 5
// 3327.884 us; speedup vs baseline: 1.5132x; 1.5132x over previous
//
#include <hip/hip_runtime.h>
#include <math.h>

// Problem constants
#define B_    8192
#define DIN_  1024
#define HID_  2048
#define LAT_  256
#define KC_   4096   // codebook size

using bfrag8 = __attribute__((ext_vector_type(8))) short;   // 8 bf16 (4 VGPR)
using facc4  = __attribute__((ext_vector_type(4))) float;   // MFMA C/D frag

__device__ __forceinline__ unsigned short f2bf(float f) {
    union { float f; unsigned int u; } c; c.f = f;
    unsigned int u = c.u;
    return (unsigned short)((u + 0x7FFFu + ((u >> 16) & 1u)) >> 16);   // RNE
}

// ---------------------------------------------------------------------------
// Encoder GEMM, fp64 accumulation, BIT-IDENTICAL k-order to round-4 kernel:
// per output element, products A[m][k]*W[k][n] are accumulated with fma in
// strictly increasing k. Changes vs R4: cvt f32->f64 hoisted to staging (LDS
// holds doubles), 8x4 thread tile (BM=128, BN=64) for 32 FMA / 12 LDS-dbl.
// ---------------------------------------------------------------------------
template <bool GELU>
__global__ __launch_bounds__(256) void gemm_bias_act_f64v2(
    const float* __restrict__ A, const float* __restrict__ W,
    const float* __restrict__ bias, float* __restrict__ C,
    int M, int N, int K)
{
    __shared__ double As[16][130];   // [k][m] 128 + pad
    __shared__ double Ws[16][66];    // [k][n] 64 + pad

    const int tid = threadIdx.x;
    const int tx = tid & 15;         // col group (4 cols)
    const int ty = tid >> 4;         // row group (8 rows)
    const int m0 = blockIdx.x * 128;
    const int n0 = blockIdx.y * 64;

    double acc[8][4] = {};

    for (int k0 = 0; k0 < K; k0 += 16) {
        // stage A tile 128x16 (cvt once here)
#pragma unroll
        for (int i = 0; i < 8; ++i) {
            const int m = ty + i * 16;
            As[tx][m] = (double)A[(size_t)(m0 + m) * K + k0 + tx];
        }
        // stage W tile 16x64
#pragma unroll
        for (int j = 0; j < 4; ++j) {
            const int kk = (tid >> 6) + j * 4;
            Ws[kk][tid & 63] = (double)W[(size_t)(k0 + kk) * N + n0 + (tid & 63)];
        }
        __syncthreads();
#pragma unroll
        for (int kk = 0; kk < 16; ++kk) {
            double a[8], b[4];
#pragma unroll
            for (int i = 0; i < 8; ++i) a[i] = As[kk][ty * 8 + i];
#pragma unroll
            for (int j = 0; j < 4; ++j) b[j] = Ws[kk][tx * 4 + j];
#pragma unroll
            for (int i = 0; i < 8; ++i)
#pragma unroll
                for (int j = 0; j < 4; ++j)
                    acc[i][j] = fma(a[i], b[j], acc[i][j]);
        }
        __syncthreads();
    }

    const int nb = n0 + tx * 4;
    const float4 bvec = *reinterpret_cast<const float4*>(&bias[nb]);
    const double bb[4] = {(double)bvec.x, (double)bvec.y, (double)bvec.z, (double)bvec.w};
#pragma unroll
    for (int i = 0; i < 8; ++i) {
        const int m = m0 + ty * 8 + i;
        float rr[4];
#pragma unroll
        for (int j = 0; j < 4; ++j) {
            double v = acc[i][j] + bb[j];
            if (GELU) v = 0.5 * v * (1.0 + erf(v * 0.70710678118654752440));
            rr[j] = (float)v;
        }
        float4 r; r.x = rr[0]; r.y = rr[1]; r.z = rr[2]; r.w = rr[3];
        *reinterpret_cast<float4*>(&C[(size_t)m * N + nb]) = r;
    }
}

// ---------------------------------------------------------------------------
// Decoder GEMM: bf16 MFMA 16x16x32, 128x128 block tile, 4 waves (2x2 of 64x64)
// A [M,K] bf16, WT [N,K] bf16 (pre-transposed weights), bias fp32.
// OUT_BF16=1: C bf16 with exact-erf GELU.  OUT_BF16=0: C fp32, no GELU.
// ---------------------------------------------------------------------------
template <int OUT_BF16>
__global__ __launch_bounds__(256) void gemm_mfma_bf16(
    const unsigned short* __restrict__ A,
    const unsigned short* __restrict__ WT,
    const float* __restrict__ bias,
    void* __restrict__ Cout,
    int M, int N, int K)
{
    __shared__ unsigned short As[128 * 64];   // [m][k], 64-k stage, 16 KB
    __shared__ unsigned short Bs[128 * 64];   // [n][k], 16 KB

    const int tid  = threadIdx.x;
    const int wave = tid >> 6;
    const int lane = tid & 63;
    const int wm   = wave & 1;        // wave row  (2x2 wave grid)
    const int wn   = wave >> 1;       // wave col
    const int quad = lane >> 4;
    const int ln   = lane & 15;
    const int m0 = blockIdx.x * 128;
    const int n0 = blockIdx.y * 128;

    facc4 acc[4][4] = {};   // zero-init

    for (int k0 = 0; k0 < K; k0 += 64) {
        // stage A and WT tiles: 1024 x 16B each, 4 iters x 256 threads
#pragma unroll
        for (int i = 0; i < 4; ++i) {
            const int idx = i * 256 + tid;
            const int row = idx >> 3;
            const int c8  = (idx & 7) * 8;
            *reinterpret_cast<bfrag8*>(&As[row * 64 + c8]) =
                *reinterpret_cast<const bfrag8*>(&A[(size_t)(m0 + row) * K + k0 + c8]);
            *reinterpret_cast<bfrag8*>(&Bs[row * 64 + c8]) =
                *reinterpret_cast<const bfrag8*>(&WT[(size_t)(n0 + row) * K + k0 + c8]);
        }
        __syncthreads();
#pragma unroll
        for (int ks = 0; ks < 64; ks += 32) {
            bfrag8 am[4], bn[4];
#pragma unroll
            for (int f = 0; f < 4; ++f) {
                am[f] = *reinterpret_cast<const bfrag8*>(
                    &As[(wm * 64 + f * 16 + ln) * 64 + ks + quad * 8]);
                bn[f] = *reinterpret_cast<const bfrag8*>(
                    &Bs[(wn * 64 + f * 16 + ln) * 64 + ks + quad * 8]);
            }
#pragma unroll
            for (int fm = 0; fm < 4; ++fm)
#pragma unroll
                for (int fn = 0; fn < 4; ++fn)
                    acc[fm][fn] = __builtin_amdgcn_mfma_f32_16x16x32_bf16(
                        am[fm], bn[fn], acc[fm][fn], 0, 0, 0);
        }
        __syncthreads();
    }

    // epilogue: C row = quad*4 + reg, col = ln (within each 16x16 tile)
#pragma unroll
    for (int fn = 0; fn < 4; ++fn) {
        const int col = n0 + wn * 64 + fn * 16 + ln;
        const float bf = bias[col];
#pragma unroll
        for (int fm = 0; fm < 4; ++fm) {
            const int rbase = m0 + wm * 64 + fm * 16 + quad * 4;
#pragma unroll
            for (int r = 0; r < 4; ++r) {
                float v = acc[fm][fn][r] + bf;
                if (OUT_BF16) {
                    v = 0.5f * v * (1.0f + erff(v * 0.70710678118654752440f));
                    ((unsigned short*)Cout)[(size_t)(rbase + r) * N + col] = f2bf(v);
                } else {
                    ((float*)Cout)[(size_t)(rbase + r) * N + col] = v;
                }
            }
        }
    }
}

// ---------------------------------------------------------------------------
// Cast+transpose weights: W [K,N] fp32 -> WT [N,K] bf16
// ---------------------------------------------------------------------------
__global__ __launch_bounds__(256) void cast_transpose_w(
    const float* __restrict__ W, unsigned short* __restrict__ WT, int K, int N)
{
    __shared__ float t[32][33];
    const int k0 = blockIdx.x * 32;
    const int n0 = blockIdx.y * 32;
    const int x = threadIdx.x;
    const int y = threadIdx.y;
#pragma unroll
    for (int i = 0; i < 4; ++i)
        t[y + i * 8][x] = W[(size_t)(k0 + y + i * 8) * N + n0 + x];
    __syncthreads();
#pragma unroll
    for (int i = 0; i < 4; ++i)
        WT[(size_t)(n0 + y + i * 8) * K + k0 + x] = f2bf(t[x][y + i * 8]);
}

// ---------------------------------------------------------------------------
// Transpose embed [4096,256] -> embedT [256,4096] (fp32, for vq_argmin)
// ---------------------------------------------------------------------------
__global__ __launch_bounds__(256) void transpose_embed(
    const float* __restrict__ E, float* __restrict__ ET)
{
    __shared__ float t[32][33];
    const int c0 = blockIdx.x * 32;
    const int l0 = blockIdx.y * 32;
    const int x = threadIdx.x;
    const int y = threadIdx.y;
#pragma unroll
    for (int i = 0; i < 4; ++i)
        t[y + i * 8][x] = E[(size_t)(c0 + y + i * 8) * LAT_ + l0 + x];
    __syncthreads();
#pragma unroll
    for (int i = 0; i < 4; ++i)
        ET[(size_t)(l0 + y + i * 8) * KC_ + c0 + x] = t[x][y + i * 8];
}

// ---------------------------------------------------------------------------
// rowsq[r] = fp32( fp64 sum of X[r,:].^2 ), rows of width LAT_=256.
// ---------------------------------------------------------------------------
__global__ __launch_bounds__(64) void rowsq_kernel(
    const float* __restrict__ X, float* __restrict__ out,
    float* __restrict__ loss_slot)
{
    const int r = blockIdx.x;
    const float4 v = reinterpret_cast<const float4*>(X + (size_t)r * LAT_)[threadIdx.x];
    double s = (double)v.x * v.x + (double)v.y * v.y + (double)v.z * v.z + (double)v.w * v.w;
#pragma unroll
    for (int off = 32; off; off >>= 1) s += __shfl_down(s, off, 64);
    if (threadIdx.x == 0) {
        out[r] = (float)s;
        if (loss_slot != nullptr && r == 0) *loss_slot = 0.0f;
    }
}

// ---------------------------------------------------------------------------
// Fused distance + argmin (unchanged from passing round 4):
//   dist32 = fp32( fp32(zsq + esq) - fp32(2 * dot_f64) ), argmin first-index.
// ---------------------------------------------------------------------------
__global__ __launch_bounds__(256) void vq_argmin(
    const float* __restrict__ Z,     // [B,256]
    const float* __restrict__ ET,    // [256,4096]
    const float* __restrict__ esq,   // [4096] fp32
    const float* __restrict__ zsq,   // [B]    fp32
    float* __restrict__ pval, int* __restrict__ pidx)  // [B,8]
{
    __shared__ float Zs[16][68];
    __shared__ float Es[16][64];
    __shared__ float rv[64][16];
    __shared__ int   ri[64][16];

    const int tid = threadIdx.x;
    const int tx = tid & 15;
    const int ty = tid >> 4;
    const int m0 = blockIdx.x * 64;
    const int split = blockIdx.y;
    const int nbeg = split * (KC_ / 8);

    float zsqv[4];
#pragma unroll
    for (int i = 0; i < 4; ++i) zsqv[i] = zsq[m0 + ty * 4 + i];

    float bestv[4];
    int   besti[4];
#pragma unroll
    for (int i = 0; i < 4; ++i) { bestv[i] = 3.4e38f; besti[i] = 0; }

    for (int n0 = nbeg; n0 < nbeg + (KC_ / 8); n0 += 64) {
        double acc[4][4] = {};
        for (int k0 = 0; k0 < LAT_; k0 += 16) {
#pragma unroll
            for (int i = 0; i < 4; ++i) {
                int m = (tid >> 4) + i * 16;
                Zs[tid & 15][m] = Z[(size_t)(m0 + m) * LAT_ + k0 + (tid & 15)];
            }
#pragma unroll
            for (int i = 0; i < 4; ++i) {
                int k = (tid >> 6) + i * 4;
                Es[k][tid & 63] = ET[(size_t)(k0 + k) * KC_ + n0 + (tid & 63)];
            }
            __syncthreads();
#pragma unroll
            for (int kk = 0; kk < 16; ++kk) {
                const float4 a = *reinterpret_cast<const float4*>(&Zs[kk][ty * 4]);
                const float4 b = *reinterpret_cast<const float4*>(&Es[kk][tx * 4]);
                const double av[4] = {(double)a.x, (double)a.y, (double)a.z, (double)a.w};
                const double bv[4] = {(double)b.x, (double)b.y, (double)b.z, (double)b.w};
#pragma unroll
                for (int i = 0; i < 4; ++i)
#pragma unroll
                    for (int j = 0; j < 4; ++j)
                        acc[i][j] = fma(av[i], bv[j], acc[i][j]);
            }
            __syncthreads();
        }
#pragma unroll
        for (int j = 0; j < 4; ++j) {
            const int n = n0 + tx * 4 + j;
            const float es = esq[n];
#pragma unroll
            for (int i = 0; i < 4; ++i) {
                const float S   = zsqv[i] + es;
                const float t2m = (float)(2.0 * acc[i][j]);
                const float sc  = S - t2m;
                if (sc < bestv[i] || (sc == bestv[i] && n < besti[i])) {
                    bestv[i] = sc; besti[i] = n;
                }
            }
        }
    }
#pragma unroll
    for (int i = 0; i < 4; ++i) { rv[ty * 4 + i][tx] = bestv[i]; ri[ty * 4 + i][tx] = besti[i]; }
    __syncthreads();
    if (tid < 64) {
        float bv = rv[tid][0]; int bi = ri[tid][0];
#pragma unroll
        for (int t = 1; t < 16; ++t) {
            const float v = rv[tid][t]; const int ix = ri[tid][t];
            if (v < bv || (v == bv && ix < bi)) { bv = v; bi = ix; }
        }
        pval[(m0 + tid) * 8 + split] = bv;
        pidx[(m0 + tid) * 8 + split] = bi;
    }
}

// ---------------------------------------------------------------------------
// Finalize: reduce 8 partials -> index (float), gather z_q (bf16), loss atomics
// ---------------------------------------------------------------------------
__global__ __launch_bounds__(64) void vq_finalize(
    const float* __restrict__ pval, const int* __restrict__ pidx,
    const float* __restrict__ Z, const float* __restrict__ E,
    unsigned short* __restrict__ zqb, float* __restrict__ out_idx,
    float* __restrict__ loss_slot)
{
    const int row = blockIdx.x;
    __shared__ int sidx;
    if (threadIdx.x == 0) {
        float bv = pval[row * 8]; int bi = pidx[row * 8];
#pragma unroll
        for (int s = 1; s < 8; ++s) {
            const float v = pval[row * 8 + s]; const int ix = pidx[row * 8 + s];
            if (v < bv || (v == bv && ix < bi)) { bv = v; bi = ix; }
        }
        sidx = bi;
        out_idx[row] = (float)bi;
    }
    __syncthreads();
    const int idx = sidx;
    const float4 e = reinterpret_cast<const float4*>(E + (size_t)idx * LAT_)[threadIdx.x];
    const float4 z = reinterpret_cast<const float4*>(Z + (size_t)row * LAT_)[threadIdx.x];
    ushort4 q; q.x = f2bf(e.x); q.y = f2bf(e.y); q.z = f2bf(e.z); q.w = f2bf(e.w);
    reinterpret_cast<ushort4*>(zqb + (size_t)row * LAT_)[threadIdx.x] = q;
    const float dx = z.x - e.x, dy = z.y - e.y, dz = z.z - e.z, dw = z.w - e.w;
    float s = dx * dx + dy * dy + dz * dz + dw * dw;
#pragma unroll
    for (int off = 32; off; off >>= 1) s += __shfl_down(s, off, 64);
    if (threadIdx.x == 0)
        atomicAdd(loss_slot, s * (1.25f / ((float)B_ * (float)LAT_)));
}

// ---------------------------------------------------------------------------
extern "C" void kernel_launch(void* const* d_in, const int* in_sizes, int n_in,
                              void* d_out, int out_size, void* d_ws, size_t ws_size,
                              hipStream_t stream)
{
    const float* x   = (const float*)d_in[0];
    const float* W1  = (const float*)d_in[1];
    const float* b1  = (const float*)d_in[2];
    const float* W2  = (const float*)d_in[3];
    const float* b2  = (const float*)d_in[4];
    const float* W3  = (const float*)d_in[5];
    const float* b3  = (const float*)d_in[6];
    const float* emb = (const float*)d_in[7];
    const float* D1  = (const float*)d_in[8];
    const float* d1  = (const float*)d_in[9];
    const float* D2  = (const float*)d_in[10];
    const float* d2  = (const float*)d_in[11];
    const float* D3  = (const float*)d_in[12];
    const float* d3  = (const float*)d_in[13];
    float* out = (float*)d_out;

    // Workspace (~145 MB used; R4 proved ≥156 MB available):
    //   [  0, 64M)  h1 fp32          -> later: g1b [0,32M), g2b [32,64M) (bf16)
    //   [ 64,128M)  h2 fp32          -> later: wt1 [64,65M), wt2 [65,73M), wt3 [73,77M)
    //   [128,136M)  ze fp32
    //   [136,140M)  zqb bf16
    //   [140,144M)  embT fp32
    //   [144M..)    esq, zsq, pval, pidx
    char* ws = (char*)d_ws;
    float* h1   = (float*)(ws);
    float* h2   = (float*)(ws + 67108864);
    float* ze   = (float*)(ws + 134217728);
    unsigned short* zqb = (unsigned short*)(ws + 142606336);
    float* embT = (float*)(ws + 146800640);
    float* esq  = (float*)(ws + 150994944);
    float* zsq  = (float*)(ws + 151011328);
    float* pval = (float*)(ws + 151044096);
    int*   pidx = (int*)  (ws + 151306240);
    unsigned short* g1b = (unsigned short*)(ws);              // over h1 (dead)
    unsigned short* g2b = (unsigned short*)(ws + 33554432);
    unsigned short* wt1 = (unsigned short*)(ws + 67108864);   // over h2 (dead)
    unsigned short* wt2 = (unsigned short*)(ws + 68157440);
    unsigned short* wt3 = (unsigned short*)(ws + 76546048);

    float* loss_slot = out + (size_t)B_ * DIN_;     // d_out[8388608]
    float* out_idx   = loss_slot + 1;               // d_out[8388609..]

    // codebook prep (esq kernel also zeroes loss slot)
    rowsq_kernel<<<KC_, 64, 0, stream>>>(emb, esq, loss_slot);
    transpose_embed<<<dim3(KC_ / 32, LAT_ / 32), dim3(32, 8), 0, stream>>>(emb, embT);

    // encoder — fp64 accumulation, bit-identical k-order (argmin-critical)
    gemm_bias_act_f64v2<true ><<<dim3(B_ / 128, HID_ / 64), 256, 0, stream>>>(x,  W1, b1, h1, B_, HID_, DIN_);
    gemm_bias_act_f64v2<true ><<<dim3(B_ / 128, HID_ / 64), 256, 0, stream>>>(h1, W2, b2, h2, B_, HID_, HID_);
    gemm_bias_act_f64v2<false><<<dim3(B_ / 128, LAT_ / 64), 256, 0, stream>>>(h2, W3, b3, ze, B_, LAT_, HID_);

    // z row norms
    rowsq_kernel<<<B_, 64, 0, stream>>>(ze, zsq, nullptr);

    // decoder weight prep (after enc3: wt* overlay h2)
    cast_transpose_w<<<dim3(LAT_ / 32, HID_ / 32), dim3(32, 8), 0, stream>>>(D1, wt1, LAT_, HID_);
    cast_transpose_w<<<dim3(HID_ / 32, HID_ / 32), dim3(32, 8), 0, stream>>>(D2, wt2, HID_, HID_);
    cast_transpose_w<<<dim3(HID_ / 32, DIN_ / 32), dim3(32, 8), 0, stream>>>(D3, wt3, HID_, DIN_);

    // VQ — numpy-fp32-mimicking scores, first-index tie-break
    vq_argmin<<<dim3(B_ / 64, 8), 256, 0, stream>>>(ze, embT, esq, zsq, pval, pidx);
    vq_finalize<<<B_, 64, 0, stream>>>(pval, pidx, ze, emb, zqb, out_idx, loss_slot);

    // decoder — bf16 MFMA (numerically free vs threshold)
    gemm_mfma_bf16<1><<<dim3(B_ / 128, HID_ / 128), 256, 0, stream>>>(zqb, wt1, d1, (void*)g1b, B_, HID_, LAT_);
    gemm_mfma_bf16<1><<<dim3(B_ / 128, HID_ / 128), 256, 0, stream>>>(g1b, wt2, d2, (void*)g2b, B_, HID_, HID_);
    gemm_mfma_bf16<0><<<dim3(B_ / 128, DIN_ / 128), 256, 0, stream>>>(g2b, wt3, d3, (void*)out, B_, DIN_, HID_);
}